// Round 13
// baseline (351.191 us; speedup 1.0000x reference)
//
#include <hip/hip_runtime.h>

// AdaTTSp on MI355X. B=32768, T=8, E=2, NE=16, D=H=128, L=2.
// Round 13 = round 12 + counted-wait barriers in kexp:
//   __syncthreads() drains vmcnt(0) (m97) — killing the async prefetch and
//   stalling ~600cy at the mid-tile barrier. Replaced with
//   lgkmcnt(0)-only + raw s_barrier (LDS ordering needs only lgkm; prefetch
//   loads land in regs, eo stores have no in-kernel consumer). sched_barrier
//   pins against compiler reordering (rule #18). Everything else == r12.

typedef float f32x4 __attribute__((ext_vector_type(4)));
typedef _Float16 f16;
typedef f16 f16x8 __attribute__((ext_vector_type(8)));
typedef f16 f16x4 __attribute__((ext_vector_type(4)));

#define MFMA(a, b, c) __builtin_amdgcn_mfma_f32_16x16x32_f16(a, b, c, 0, 0, 0)
#define LOSC (1.0f / 2048.0f)

__device__ __forceinline__ void split2h(float f, f16& h, f16& l) {
  h = (f16)f;
  l = (f16)((f - (float)h) * 2048.0f);
}

// barrier with lgkm-only drain: orders LDS producer->consumer across waves
// without draining in-flight global loads/stores (vmcnt stays counted).
__device__ __forceinline__ void bar_lgkm() {
  __builtin_amdgcn_sched_barrier(0);
  asm volatile("s_waitcnt lgkmcnt(0)" ::: "memory");
  __builtin_amdgcn_s_barrier();
  __builtin_amdgcn_sched_barrier(0);
}

// ---------------------------------------------------------------------------
// x0 f32 -> fp16, natural [B][T][D] layout.
__global__ __launch_bounds__(256) void kxcast(const float* __restrict__ x0,
                                              f16* __restrict__ x0h) {
  size_t i = ((size_t)blockIdx.x * 256 + threadIdx.x) * 8;
  f32x4 f0 = *(const f32x4*)(x0 + i);
  f32x4 f1 = *(const f32x4*)(x0 + i + 4);
  f16x8 v;
#pragma unroll
  for (int z = 0; z < 4; ++z) {
    v[z] = (f16)f0[z];
    v[4 + z] = (f16)f1[z];
  }
  *(f16x8*)(x0h + i) = v;
}

// ---------------------------------------------------------------------------
// Weight transform -> fp16 hi/lo fragment arrays (identical to r8-r12).
__global__ __launch_bounds__(256) void kxform(
    const float* __restrict__ w1, const float* __restrict__ w2,
    const float* __restrict__ gw, f16* __restrict__ w1T,
    f16* __restrict__ w2T, f16* __restrict__ gwT) {
  int idx = blockIdx.x * 256 + threadIdx.x;
  if (idx < 131072) {
    const float* src = (idx < 65536) ? w1 : w2;
    f16* dst = (idx < 65536) ? w1T : w2T;
    int i = idx & 65535;
    int lane = i & 63;
    int it = (i >> 6) & 7;
    int ks = (i >> 9) & 3;
    int q = i >> 11;
    int g = lane >> 4, le = lane & 15;
    f16x8 vh, vl;
#pragma unroll
    for (int j = 0; j < 8; ++j) {
      float f = src[((size_t)q * 128 + (32 * ks + 8 * g + j)) * 128 + 16 * it + le];
      f16 h, l;
      split2h(f, h, l);
      vh[j] = h;
      vl[j] = l;
    }
    *(f16x8*)(dst + (size_t)i * 8) = vh;
    *(f16x8*)(dst + 524288 + (size_t)i * 8) = vl;
  } else {
    int i = idx - 131072;
    if (i >= 4096) return;
    int lane = i & 63;
    int ks = (i >> 6) & 3;
    int q = (i >> 8) & 15;
    int g = lane >> 4, le = lane & 15;
    f16x8 vh, vl;
#pragma unroll
    for (int j = 0; j < 8; ++j) {
      float f = gw[((size_t)q * 128 + (32 * ks + 8 * g + j)) * 16 + le];
      f16 h, l;
      split2h(f, h, l);
      vh[j] = h;
      vl[j] = l;
    }
    *(f16x8*)(gwT + (size_t)i * 8) = vh;
    *(f16x8*)(gwT + 32768 + (size_t)i * 8) = vl;
  }
}

// ---------------------------------------------------------------------------
// Expert kernel. grid = 32 chunks(1024 rows) x 16 experts; 256 thr (4 waves).
// Wave = it2 (oc 32-col tile). Weights in regs. 64-row dbuf tiles,
// async-staged: load@top-of-tile, write@after-GEMM2. lgkm-only barriers.
// LDS x/h swizzle: elem [row][c] at row*128 + 8*((c>>3)^(row&7)) + (c&7).
__global__ __launch_bounds__(256, 2) void kexp(
    const f16* __restrict__ xs, const f16* __restrict__ w1T,
    const f16* __restrict__ w2T, const float* __restrict__ b1,
    const float* __restrict__ b2, f16* __restrict__ eo, int layer) {
  __shared__ f16 sX[2][8192];  // 64 x 128, double-buffered (32KB)
  __shared__ f16 sH[8192];     // 16KB
  const int tid = threadIdx.x;
  const int lane = tid & 63;
  const int it2 = tid >> 6;
  const int g = lane >> 4, le = lane & 15;
  const int e = blockIdx.x & 15;
  const int r0 = (blockIdx.x >> 4) * 1024;
  const int te = e >> 1;
  const int lx = layer * 16 + e;

  // ---- resident weight fragments (it = 2*it2 + i2) ----
  f16x8 w1h[2][4], w1l[2][4], w2h[2][4], w2l[2][4];
#pragma unroll
  for (int i2 = 0; i2 < 2; ++i2)
#pragma unroll
    for (int ks = 0; ks < 4; ++ks) {
      size_t fb = ((size_t)((lx * 4 + ks) * 8 + 2 * it2 + i2) * 64 + lane) * 8;
      w1h[i2][ks] = *(const f16x8*)(w1T + fb);
      w1l[i2][ks] = *(const f16x8*)(w1T + 524288 + fb);
      w2h[i2][ks] = *(const f16x8*)(w2T + fb);
      w2l[i2][ks] = *(const f16x8*)(w2T + 524288 + fb);
    }
  f32x4 b1v[2], b2v[2];
#pragma unroll
  for (int i2 = 0; i2 < 2; ++i2) {
    b1v[i2] = *(const f32x4*)(b1 + lx * 128 + 32 * it2 + 16 * i2 + 4 * g);
    b2v[i2] = *(const f32x4*)(b2 + lx * 128 + 32 * it2 + 16 * i2 + 4 * g);
  }

  // ---- async staging: thread covers row = tid>>2, granules G0..G0+3 ----
  const int srow = tid >> 2;
  const int G0 = (tid & 3) * 4;
  f16x8 pre[4];
  auto stage_load = [&](int tile) {
    size_t gb = ((size_t)(r0 + tile * 64 + srow) * 8 + te) * 128 + G0 * 8;
#pragma unroll
    for (int q = 0; q < 4; ++q) pre[q] = *(const f16x8*)(xs + gb + q * 8);
  };
  auto stage_write = [&](int buf) {
    f16* dst = &sX[buf][srow * 128];
#pragma unroll
    for (int q = 0; q < 4; ++q)
      *(f16x8*)(dst + 8 * ((G0 + q) ^ (srow & 7))) = pre[q];
  };

  stage_load(0);
  stage_write(0);
  bar_lgkm();

  for (int tile = 0; tile < 16; ++tile) {
    const int b = tile & 1;
    // ---- issue next tile's global loads (stay in flight across barriers)
    if (tile < 15) stage_load(tile + 1);
    // ---- GEMM1: h = relu(w1^T x^T + b1) -> sH ----
    {
      f32x4 a1[2][4], a2[2][4];
#pragma unroll
      for (int i2 = 0; i2 < 2; ++i2)
#pragma unroll
        for (int j = 0; j < 4; ++j) {
          a1[i2][j] = f32x4{0.f, 0.f, 0.f, 0.f};
          a2[i2][j] = f32x4{0.f, 0.f, 0.f, 0.f};
        }
#pragma unroll
      for (int ks = 0; ks < 4; ++ks)
#pragma unroll
        for (int j = 0; j < 4; ++j) {
          int brow = 16 * j + le;
          f16x8 bf = *(const f16x8*)(&sX[b][brow * 128 + 8 * ((4 * ks + g) ^ (brow & 7))]);
#pragma unroll
          for (int i2 = 0; i2 < 2; ++i2) {
            a1[i2][j] = MFMA(w1h[i2][ks], bf, a1[i2][j]);
            a2[i2][j] = MFMA(w1l[i2][ks], bf, a2[i2][j]);
          }
        }
#pragma unroll
      for (int i2 = 0; i2 < 2; ++i2)
#pragma unroll
        for (int j = 0; j < 4; ++j) {
          int brow = 16 * j + le;
          f16x4 hv;
#pragma unroll
          for (int r = 0; r < 4; ++r)
            hv[r] = (f16)fmaxf(a1[i2][j][r] + a2[i2][j][r] * LOSC + b1v[i2][r], 0.f);
          *(f16x4*)(&sH[brow * 128 + 8 * ((4 * it2 + 2 * i2 + (g >> 1)) ^ (brow & 7)) +
                        4 * (g & 1)]) = hv;
        }
    }
    bar_lgkm();  // sH visible; prefetch loads + eo stores stay in flight
    // ---- GEMM2: eo = relu(w2^T h^T + b2) -> global fp16 ----
    {
      f32x4 a1[2][4], a2[2][4];
#pragma unroll
      for (int i2 = 0; i2 < 2; ++i2)
#pragma unroll
        for (int j = 0; j < 4; ++j) {
          a1[i2][j] = f32x4{0.f, 0.f, 0.f, 0.f};
          a2[i2][j] = f32x4{0.f, 0.f, 0.f, 0.f};
        }
#pragma unroll
      for (int ks = 0; ks < 4; ++ks)
#pragma unroll
        for (int j = 0; j < 4; ++j) {
          int brow = 16 * j + le;
          f16x8 bf = *(const f16x8*)(&sH[brow * 128 + 8 * ((4 * ks + g) ^ (brow & 7))]);
#pragma unroll
          for (int i2 = 0; i2 < 2; ++i2) {
            a1[i2][j] = MFMA(w2h[i2][ks], bf, a1[i2][j]);
            a2[i2][j] = MFMA(w2l[i2][ks], bf, a2[i2][j]);
          }
        }
#pragma unroll
      for (int i2 = 0; i2 < 2; ++i2)
#pragma unroll
        for (int j = 0; j < 4; ++j) {
          int grow = r0 + tile * 64 + 16 * j + le;
          f16x4 ev;
#pragma unroll
          for (int r = 0; r < 4; ++r)
            ev[r] = (f16)fmaxf(a1[i2][j][r] + a2[i2][j][r] * LOSC + b2v[i2][r], 0.f);
          *(f16x4*)(eo + ((size_t)grow * 16 + e) * 128 + 32 * it2 + 16 * i2 + 4 * g) = ev;
        }
    }
    // ---- write next tile's staged regs (vmcnt wait = dependency only) ----
    if (tile < 15) stage_write(b ^ 1);
    bar_lgkm();
  }
}

// ---------------------------------------------------------------------------
// Gate + mix kernel. grid = 1024 blocks (32 rows), 512 thr (8 waves).
__global__ __launch_bounds__(512, 4) void kmix(
    const f16* __restrict__ xs, const f16* __restrict__ gwT,
    const float* __restrict__ gb, const float* __restrict__ sw,
    const f16* __restrict__ eo, f16* __restrict__ x1out,
    float* __restrict__ fout, int layer) {
  __shared__ float sG[8 * 16 * 32];  // [t][e][row32] 16KB
  const int tid = threadIdx.x;
  const int lane = tid & 63;
  const int t = tid >> 6;  // wave = task
  const int g = lane >> 4, le = lane & 15;
  const int r0 = blockIdx.x * 32;
  const int lt = layer * 8 + t;

  {  // ---- gates ----
    f32x4 l1[2], l2[2];
#pragma unroll
    for (int j = 0; j < 2; ++j) {
      l1[j] = f32x4{0.f, 0.f, 0.f, 0.f};
      l2[j] = f32x4{0.f, 0.f, 0.f, 0.f};
    }
#pragma unroll
    for (int ks = 0; ks < 4; ++ks) {
      size_t fb = ((size_t)(lt * 4 + ks) * 64 + lane) * 8;
      f16x8 ah = *(const f16x8*)(gwT + fb);
      f16x8 al = *(const f16x8*)(gwT + 32768 + fb);
#pragma unroll
      for (int j = 0; j < 2; ++j) {
        f16x8 bf = *(const f16x8*)(xs + ((size_t)(r0 + 16 * j + le) * 8 + t) * 128 +
                                   32 * ks + 8 * g);
        l1[j] = MFMA(ah, bf, l1[j]);
        l2[j] = MFMA(al, bf, l2[j]);
      }
    }
#pragma unroll
    for (int j = 0; j < 2; ++j) {
      float zb[4];
#pragma unroll
      for (int r = 0; r < 4; ++r)
        zb[r] = l1[j][r] + l2[j][r] * LOSC + gb[lt * 16 + 4 * g + r];
      float m4 = fmaxf(fmaxf(zb[0], zb[1]), fmaxf(zb[2], zb[3]));
      m4 = fmaxf(m4, __shfl_xor(m4, 16, 64));
      m4 = fmaxf(m4, __shfl_xor(m4, 32, 64));
      float p4[4], s4 = 0.f;
#pragma unroll
      for (int r = 0; r < 4; ++r) {
        p4[r] = __expf(zb[r] - m4);
        s4 += p4[r];
      }
      s4 += __shfl_xor(s4, 16, 64);
      s4 += __shfl_xor(s4, 32, 64);
      float inv = 1.f / s4;
#pragma unroll
      for (int r = 0; r < 4; ++r)
        sG[(t * 16 + 4 * g + r) * 32 + 16 * j + le] = p4[r] * inv;
    }
  }
  __syncthreads();

  // ---- mix ----
  const int lrow = tid >> 4;
  const int grow = r0 + lrow;
  const int c0 = (tid & 15) * 8;
  f32x4 am[8][2];
#pragma unroll
  for (int tt = 0; tt < 8; ++tt)
#pragma unroll
    for (int k = 0; k < 2; ++k) am[tt][k] = f32x4{0.f, 0.f, 0.f, 0.f};

  for (int e = 0; e < 16; ++e) {
    const int te = e >> 1, eh = e & 1;
    f16x8 ev = *(const f16x8*)(eo + ((size_t)grow * 16 + e) * 128 + c0);
    float evf[8];
#pragma unroll
    for (int z = 0; z < 8; ++z) evf[z] = (float)ev[z];
    float ssew = sw[(layer * 8 + te) * 2 + eh];
#pragma unroll
    for (int tt = 0; tt < 8; ++tt) {
      float coef = sG[(tt * 16 + e) * 32 + lrow] + (tt == te ? ssew : 0.f);
#pragma unroll
      for (int z = 0; z < 8; ++z)
        am[tt][z >> 2][z & 3] = fmaf(coef, evf[z], am[tt][z >> 2][z & 3]);
    }
  }
#pragma unroll
  for (int tt = 0; tt < 8; ++tt) {
    size_t off = ((size_t)grow * 8 + tt) * 128 + c0;
    if (layer == 0) {
      f16x8 hv;
#pragma unroll
      for (int z = 0; z < 8; ++z) hv[z] = (f16)am[tt][z >> 2][z & 3];
      *(f16x8*)(x1out + off) = hv;
    } else {
      *(f32x4*)(fout + off) = am[tt][0];
      *(f32x4*)(fout + off + 4) = am[tt][1];
    }
  }
}

// ---------------------------------------------------------------------------
extern "C" void kernel_launch(void* const* d_in, const int* in_sizes, int n_in,
                              void* d_out, int out_size, void* d_ws, size_t ws_size,
                              hipStream_t stream) {
  const float* x0 = (const float*)d_in[0];
  const float* w1 = (const float*)d_in[1];
  const float* b1 = (const float*)d_in[2];
  const float* w2 = (const float*)d_in[3];
  const float* b2 = (const float*)d_in[4];
  const float* gw = (const float*)d_in[5];
  const float* gb = (const float*)d_in[6];
  const float* sw = (const float*)d_in[7];

  // ws bytes: w1T pair [0,2MB) | w2T pair [2MB,4MB) | gwT pair [4MB,+128KB)
  // | x0h fp16 [8MB,+64MB) | x1h fp16 [72MB,+64MB) | eo fp16 [136MB,+128MB)
  f16* w1T = (f16*)d_ws;
  f16* w2T = (f16*)((char*)d_ws + 2097152);
  f16* gwT = (f16*)((char*)d_ws + 4194304);
  f16* x0h = (f16*)((char*)d_ws + 8388608);
  f16* x1h = (f16*)((char*)d_ws + 75497472);
  f16* eo = (f16*)((char*)d_ws + 142606336);
  float* out = (float*)d_out;

  kxform<<<528, 256, 0, stream>>>(w1, w2, gw, w1T, w2T, gwT);
  kxcast<<<16384, 256, 0, stream>>>(x0, x0h);

  kexp<<<512, 256, 0, stream>>>(x0h, w1T, w2T, b1, b2, eo, 0);
  kmix<<<1024, 512, 0, stream>>>(x0h, gwT, gb, sw, eo, x1h, nullptr, 0);
  kexp<<<512, 256, 0, stream>>>(x1h, w1T, w2T, b1, b2, eo, 1);
  kmix<<<1024, 512, 0, stream>>>(x1h, gwT, gb, sw, eo, nullptr, out, 1);
}

// Round 14
// 318.700 us; speedup vs baseline: 1.1020x; 1.1020x over previous
//
#include <hip/hip_runtime.h>

// AdaTTSp on MI355X. B=32768, T=8, E=2, NE=16, D=H=128, L=2.
// Round 14: r12 structure with (a) single-fp16 expert weights (halves MFMA,
// weights now truly fit in VGPR: 64 regs, asm-pinned vs rematerialization —
// r12's VGPR_Count=128 proved the hi/lo weights were being reloaded every
// tile), (b) 32-row tiles + grid 1024 -> 4 blocks/CU, 4 waves/SIMD (2x r12
// occupancy so MFMA/LDS/VMEM pipes overlap), (c) __syncthreads restored
// (r13's counted-wait barriers regressed), (d) kxcast dropped (layer 0
// reads f32 directly). Gate weights keep hi/lo (cheap, protects softmax).

typedef float f32x4 __attribute__((ext_vector_type(4)));
typedef _Float16 f16;
typedef f16 f16x8 __attribute__((ext_vector_type(8)));
typedef f16 f16x4 __attribute__((ext_vector_type(4)));

#define MFMA(a, b, c) __builtin_amdgcn_mfma_f32_16x16x32_f16(a, b, c, 0, 0, 0)
#define LOSC (1.0f / 2048.0f)

__device__ __forceinline__ void split2h(float f, f16& h, f16& l) {
  h = (f16)f;
  l = (f16)((f - (float)h) * 2048.0f);
}

// ---------------------------------------------------------------------------
// Weight transform. w1T/w2T: SINGLE fp16 fragment arrays:
//   wT[q][ks][it][lane][j] = w[q][d = 32*ks + 8*(lane>>4) + j][m = 16*it + (lane&15)]
// gwT: hi/lo pair (lo at +32768), layout [q=l*8+t][ks][lane][j].
__global__ __launch_bounds__(256) void kxform(
    const float* __restrict__ w1, const float* __restrict__ w2,
    const float* __restrict__ gw, f16* __restrict__ w1T,
    f16* __restrict__ w2T, f16* __restrict__ gwT) {
  int idx = blockIdx.x * 256 + threadIdx.x;
  if (idx < 131072) {
    const float* src = (idx < 65536) ? w1 : w2;
    f16* dst = (idx < 65536) ? w1T : w2T;
    int i = idx & 65535;
    int lane = i & 63;
    int it = (i >> 6) & 7;
    int ks = (i >> 9) & 3;
    int q = i >> 11;
    int g = lane >> 4, le = lane & 15;
    f16x8 vh;
#pragma unroll
    for (int j = 0; j < 8; ++j)
      vh[j] = (f16)src[((size_t)q * 128 + (32 * ks + 8 * g + j)) * 128 + 16 * it + le];
    *(f16x8*)(dst + (size_t)i * 8) = vh;
  } else {
    int i = idx - 131072;
    if (i >= 4096) return;
    int lane = i & 63;
    int ks = (i >> 6) & 3;
    int q = (i >> 8) & 15;
    int g = lane >> 4, le = lane & 15;
    f16x8 vh, vl;
#pragma unroll
    for (int j = 0; j < 8; ++j) {
      float f = gw[((size_t)q * 128 + (32 * ks + 8 * g + j)) * 16 + le];
      f16 h, l;
      split2h(f, h, l);
      vh[j] = h;
      vl[j] = l;
    }
    *(f16x8*)(gwT + (size_t)i * 8) = vh;
    *(f16x8*)(gwT + 32768 + (size_t)i * 8) = vl;
  }
}

// ---------------------------------------------------------------------------
// Expert kernel. grid = 64 chunks(512 rows) x 16 experts = 1024 blocks;
// 256 thr (4 waves), 4 blocks/CU (LDS 24KB, lb(256,4)). Wave = it2 (32 oc).
// 16 tiles of 32 rows, async-staged (load@top, write@after-GEMM2).
// LDS x/h swizzle: elem [row][c] at row*128 + 8*((c>>3)^(row&7)) + (c&7).
__global__ __launch_bounds__(256, 4) void kexp(
    const float* __restrict__ x0, const f16* __restrict__ x1in,
    const f16* __restrict__ w1T, const f16* __restrict__ w2T,
    const float* __restrict__ b1, const float* __restrict__ b2,
    f16* __restrict__ eo, int layer) {
  __shared__ f16 sX[2][4096];  // 32 x 128, double-buffered (16KB)
  __shared__ f16 sH[4096];     // 8KB
  const int tid = threadIdx.x;
  const int lane = tid & 63;
  const int it2 = tid >> 6;
  const int g = lane >> 4, le = lane & 15;
  const int e = blockIdx.x & 15;
  const int r0 = (blockIdx.x >> 4) * 512;
  const int te = e >> 1;
  const int lx = layer * 16 + e;

  // ---- resident single-fp16 weight fragments (it = 2*it2 + i2): 64 VGPR ----
  f16x8 w1r[2][4], w2r[2][4];
#pragma unroll
  for (int i2 = 0; i2 < 2; ++i2)
#pragma unroll
    for (int ks = 0; ks < 4; ++ks) {
      size_t fb = ((size_t)((lx * 4 + ks) * 8 + 2 * it2 + i2) * 64 + lane) * 8;
      w1r[i2][ks] = *(const f16x8*)(w1T + fb);
      w2r[i2][ks] = *(const f16x8*)(w2T + fb);
    }
  // pin against rematerialization (r12: compiler reloaded weights every tile)
#pragma unroll
  for (int i2 = 0; i2 < 2; ++i2)
#pragma unroll
    for (int ks = 0; ks < 4; ++ks) {
      asm volatile("" : "+v"(w1r[i2][ks]));
      asm volatile("" : "+v"(w2r[i2][ks]));
    }
  f32x4 b1v[2], b2v[2];
#pragma unroll
  for (int i2 = 0; i2 < 2; ++i2) {
    b1v[i2] = *(const f32x4*)(b1 + lx * 128 + 32 * it2 + 16 * i2 + 4 * g);
    b2v[i2] = *(const f32x4*)(b2 + lx * 128 + 32 * it2 + 16 * i2 + 4 * g);
  }

  // ---- async staging: thread -> row = tid>>3, granules gr, gr+1 ----
  const int srow = tid >> 3;
  const int gr = (tid & 7) * 2;
  f16x8 pre[2];
  auto stage_load = [&](int tile) {
    size_t base = ((size_t)(r0 + tile * 32 + srow) * 8 + te) * 128 + gr * 8;
    if (layer == 0) {
#pragma unroll
      for (int q = 0; q < 2; ++q) {
        f32x4 f0 = *(const f32x4*)(x0 + base + q * 8);
        f32x4 f1 = *(const f32x4*)(x0 + base + q * 8 + 4);
#pragma unroll
        for (int z = 0; z < 4; ++z) {
          pre[q][z] = (f16)f0[z];
          pre[q][4 + z] = (f16)f1[z];
        }
      }
    } else {
#pragma unroll
      for (int q = 0; q < 2; ++q)
        pre[q] = *(const f16x8*)(x1in + base + q * 8);
    }
  };
  auto stage_write = [&](int buf) {
#pragma unroll
    for (int q = 0; q < 2; ++q)
      *(f16x8*)(&sX[buf][srow * 128 + 8 * ((gr + q) ^ (srow & 7))]) = pre[q];
  };

  stage_load(0);
  stage_write(0);
  __syncthreads();

  for (int tile = 0; tile < 16; ++tile) {
    const int b = tile & 1;
    if (tile < 15) stage_load(tile + 1);
    // ---- GEMM1: h = relu(w1^T x^T + b1) -> sH ----
    {
      f32x4 a[2][2];
#pragma unroll
      for (int i2 = 0; i2 < 2; ++i2)
#pragma unroll
        for (int j = 0; j < 2; ++j) a[i2][j] = f32x4{0.f, 0.f, 0.f, 0.f};
#pragma unroll
      for (int ks = 0; ks < 4; ++ks)
#pragma unroll
        for (int j = 0; j < 2; ++j) {
          int brow = 16 * j + le;
          f16x8 bf = *(const f16x8*)(&sX[b][brow * 128 + 8 * ((4 * ks + g) ^ (brow & 7))]);
#pragma unroll
          for (int i2 = 0; i2 < 2; ++i2)
            a[i2][j] = MFMA(w1r[i2][ks], bf, a[i2][j]);
        }
#pragma unroll
      for (int i2 = 0; i2 < 2; ++i2)
#pragma unroll
        for (int j = 0; j < 2; ++j) {
          int brow = 16 * j + le;
          f16x4 hv;
#pragma unroll
          for (int r = 0; r < 4; ++r)
            hv[r] = (f16)fmaxf(a[i2][j][r] + b1v[i2][r], 0.f);
          *(f16x4*)(&sH[brow * 128 + 8 * ((4 * it2 + 2 * i2 + (g >> 1)) ^ (brow & 7)) +
                        4 * (g & 1)]) = hv;
        }
    }
    __syncthreads();
    // ---- GEMM2: eo = relu(w2^T h^T + b2) -> global fp16 ----
    {
      f32x4 a[2][2];
#pragma unroll
      for (int i2 = 0; i2 < 2; ++i2)
#pragma unroll
        for (int j = 0; j < 2; ++j) a[i2][j] = f32x4{0.f, 0.f, 0.f, 0.f};
#pragma unroll
      for (int ks = 0; ks < 4; ++ks)
#pragma unroll
        for (int j = 0; j < 2; ++j) {
          int brow = 16 * j + le;
          f16x8 bf = *(const f16x8*)(&sH[brow * 128 + 8 * ((4 * ks + g) ^ (brow & 7))]);
#pragma unroll
          for (int i2 = 0; i2 < 2; ++i2)
            a[i2][j] = MFMA(w2r[i2][ks], bf, a[i2][j]);
        }
#pragma unroll
      for (int i2 = 0; i2 < 2; ++i2)
#pragma unroll
        for (int j = 0; j < 2; ++j) {
          int grow = r0 + tile * 32 + 16 * j + le;
          f16x4 ev;
#pragma unroll
          for (int r = 0; r < 4; ++r)
            ev[r] = (f16)fmaxf(a[i2][j][r] + b2v[i2][r], 0.f);
          *(f16x4*)(eo + ((size_t)grow * 16 + e) * 128 + 32 * it2 + 16 * i2 + 4 * g) = ev;
        }
    }
    if (tile < 15) stage_write(b ^ 1);
    __syncthreads();
  }
}

// ---------------------------------------------------------------------------
// Gate + mix kernel. grid = 1024 blocks (32 rows), 512 thr (8 waves).
// Phase 1: wave = task, gate MFMA (hi/lo gw; x from f32 l0 / fp16 l1) +
// shfl softmax. Phase 2: register-tiled mix over 16 experts.
__global__ __launch_bounds__(512, 4) void kmix(
    const float* __restrict__ x0, const f16* __restrict__ x1in,
    const f16* __restrict__ gwT, const float* __restrict__ gb,
    const float* __restrict__ sw, const f16* __restrict__ eo,
    f16* __restrict__ x1out, float* __restrict__ fout, int layer) {
  __shared__ float sG[8 * 16 * 32];  // [t][e][row32] 16KB
  const int tid = threadIdx.x;
  const int lane = tid & 63;
  const int t = tid >> 6;  // wave = task
  const int g = lane >> 4, le = lane & 15;
  const int r0 = blockIdx.x * 32;
  const int lt = layer * 8 + t;

  {  // ---- gates ----
    f32x4 l1[2], l2[2];
#pragma unroll
    for (int j = 0; j < 2; ++j) {
      l1[j] = f32x4{0.f, 0.f, 0.f, 0.f};
      l2[j] = f32x4{0.f, 0.f, 0.f, 0.f};
    }
#pragma unroll
    for (int ks = 0; ks < 4; ++ks) {
      size_t fb = ((size_t)(lt * 4 + ks) * 64 + lane) * 8;
      f16x8 ah = *(const f16x8*)(gwT + fb);
      f16x8 al = *(const f16x8*)(gwT + 32768 + fb);
#pragma unroll
      for (int j = 0; j < 2; ++j) {
        size_t xoff = ((size_t)(r0 + 16 * j + le) * 8 + t) * 128 + 32 * ks + 8 * g;
        f16x8 bf;
        if (layer == 0) {
          f32x4 f0 = *(const f32x4*)(x0 + xoff);
          f32x4 f1 = *(const f32x4*)(x0 + xoff + 4);
#pragma unroll
          for (int z = 0; z < 4; ++z) {
            bf[z] = (f16)f0[z];
            bf[4 + z] = (f16)f1[z];
          }
        } else {
          bf = *(const f16x8*)(x1in + xoff);
        }
        l1[j] = MFMA(ah, bf, l1[j]);
        l2[j] = MFMA(al, bf, l2[j]);
      }
    }
#pragma unroll
    for (int j = 0; j < 2; ++j) {
      float zb[4];
#pragma unroll
      for (int r = 0; r < 4; ++r)
        zb[r] = l1[j][r] + l2[j][r] * LOSC + gb[lt * 16 + 4 * g + r];
      float m4 = fmaxf(fmaxf(zb[0], zb[1]), fmaxf(zb[2], zb[3]));
      m4 = fmaxf(m4, __shfl_xor(m4, 16, 64));
      m4 = fmaxf(m4, __shfl_xor(m4, 32, 64));
      float p4[4], s4 = 0.f;
#pragma unroll
      for (int r = 0; r < 4; ++r) {
        p4[r] = __expf(zb[r] - m4);
        s4 += p4[r];
      }
      s4 += __shfl_xor(s4, 16, 64);
      s4 += __shfl_xor(s4, 32, 64);
      float inv = 1.f / s4;
#pragma unroll
      for (int r = 0; r < 4; ++r)
        sG[(t * 16 + 4 * g + r) * 32 + 16 * j + le] = p4[r] * inv;
    }
  }
  __syncthreads();

  // ---- mix ----
  const int lrow = tid >> 4;
  const int grow = r0 + lrow;
  const int c0 = (tid & 15) * 8;
  f32x4 am[8][2];
#pragma unroll
  for (int tt = 0; tt < 8; ++tt)
#pragma unroll
    for (int k = 0; k < 2; ++k) am[tt][k] = f32x4{0.f, 0.f, 0.f, 0.f};

  for (int ee = 0; ee < 16; ++ee) {
    const int te = ee >> 1, eh = ee & 1;
    f16x8 ev = *(const f16x8*)(eo + ((size_t)grow * 16 + ee) * 128 + c0);
    float evf[8];
#pragma unroll
    for (int z = 0; z < 8; ++z) evf[z] = (float)ev[z];
    float ssew = sw[(layer * 8 + te) * 2 + eh];
#pragma unroll
    for (int tt = 0; tt < 8; ++tt) {
      float coef = sG[(tt * 16 + ee) * 32 + lrow] + (tt == te ? ssew : 0.f);
#pragma unroll
      for (int z = 0; z < 8; ++z)
        am[tt][z >> 2][z & 3] = fmaf(coef, evf[z], am[tt][z >> 2][z & 3]);
    }
  }
#pragma unroll
  for (int tt = 0; tt < 8; ++tt) {
    size_t off = ((size_t)grow * 8 + tt) * 128 + c0;
    if (layer == 0) {
      f16x8 hv;
#pragma unroll
      for (int z = 0; z < 8; ++z) hv[z] = (f16)am[tt][z >> 2][z & 3];
      *(f16x8*)(x1out + off) = hv;
    } else {
      *(f32x4*)(fout + off) = am[tt][0];
      *(f32x4*)(fout + off + 4) = am[tt][1];
    }
  }
}

// ---------------------------------------------------------------------------
extern "C" void kernel_launch(void* const* d_in, const int* in_sizes, int n_in,
                              void* d_out, int out_size, void* d_ws, size_t ws_size,
                              hipStream_t stream) {
  const float* x0 = (const float*)d_in[0];
  const float* w1 = (const float*)d_in[1];
  const float* b1 = (const float*)d_in[2];
  const float* w2 = (const float*)d_in[3];
  const float* b2 = (const float*)d_in[4];
  const float* gw = (const float*)d_in[5];
  const float* gb = (const float*)d_in[6];
  const float* sw = (const float*)d_in[7];

  // ws bytes: w1T [0,1MB) | w2T [1MB,2MB) | gwT pair [2MB,+128KB)
  // | x1h fp16 [4MB,+64MB) | eo fp16 [68MB,+128MB)  => 196MB total
  f16* w1T = (f16*)d_ws;
  f16* w2T = (f16*)((char*)d_ws + 1048576);
  f16* gwT = (f16*)((char*)d_ws + 2097152);
  f16* x1h = (f16*)((char*)d_ws + 4194304);
  f16* eo = (f16*)((char*)d_ws + 71303168);
  float* out = (float*)d_out;

  kxform<<<528, 256, 0, stream>>>(w1, w2, gw, w1T, w2T, gwT);

  kexp<<<1024, 256, 0, stream>>>(x0, nullptr, w1T, w2T, b1, b2, eo, 0);
  kmix<<<1024, 512, 0, stream>>>(x0, nullptr, gwT, gb, sw, eo, x1h, nullptr, 0);
  kexp<<<1024, 256, 0, stream>>>(nullptr, x1h, w1T, w2T, b1, b2, eo, 1);
  kmix<<<1024, 512, 0, stream>>>(nullptr, x1h, gwT, gb, sw, eo, nullptr, out, 1);
}

// Round 15
// 290.526 us; speedup vs baseline: 1.2088x; 1.0970x over previous
//
#include <hip/hip_runtime.h>

// AdaTTSp on MI355X. B=32768, T=8, E=2, NE=16, D=H=128, L=2.
// Round 15: r14 + coalesced eo writes + real weight pinning.
//  - eo fragments go to sEO (LDS, XOR-swizzled, conflict-free) and are
//    flushed next tile as full-line 16B/lane contiguous stores (fixes the
//    32B/line fragment scatter that capped write BW at 1.3 TB/s, r11-r14)
//  - weight-residency pin INSIDE the tile loop (r14's init-time pin failed:
//    VGPR_Count=64 proved rematerialization)
//  - 64-row tiles (2 barriers per 64 rows), LDS 64KB, 2 blocks/CU
// kmix/kxform unchanged (kmix eo reads verified coalesced already).

typedef float f32x4 __attribute__((ext_vector_type(4)));
typedef _Float16 f16;
typedef f16 f16x8 __attribute__((ext_vector_type(8)));
typedef f16 f16x4 __attribute__((ext_vector_type(4)));

#define MFMA(a, b, c) __builtin_amdgcn_mfma_f32_16x16x32_f16(a, b, c, 0, 0, 0)
#define LOSC (1.0f / 2048.0f)

__device__ __forceinline__ void split2h(float f, f16& h, f16& l) {
  h = (f16)f;
  l = (f16)((f - (float)h) * 2048.0f);
}

// ---------------------------------------------------------------------------
// Weight transform. w1T/w2T: single-fp16 fragment arrays; gwT hi/lo pair.
__global__ __launch_bounds__(256) void kxform(
    const float* __restrict__ w1, const float* __restrict__ w2,
    const float* __restrict__ gw, f16* __restrict__ w1T,
    f16* __restrict__ w2T, f16* __restrict__ gwT) {
  int idx = blockIdx.x * 256 + threadIdx.x;
  if (idx < 131072) {
    const float* src = (idx < 65536) ? w1 : w2;
    f16* dst = (idx < 65536) ? w1T : w2T;
    int i = idx & 65535;
    int lane = i & 63;
    int it = (i >> 6) & 7;
    int ks = (i >> 9) & 3;
    int q = i >> 11;
    int g = lane >> 4, le = lane & 15;
    f16x8 vh;
#pragma unroll
    for (int j = 0; j < 8; ++j)
      vh[j] = (f16)src[((size_t)q * 128 + (32 * ks + 8 * g + j)) * 128 + 16 * it + le];
    *(f16x8*)(dst + (size_t)i * 8) = vh;
  } else {
    int i = idx - 131072;
    if (i >= 4096) return;
    int lane = i & 63;
    int ks = (i >> 6) & 3;
    int q = (i >> 8) & 15;
    int g = lane >> 4, le = lane & 15;
    f16x8 vh, vl;
#pragma unroll
    for (int j = 0; j < 8; ++j) {
      float f = gw[((size_t)q * 128 + (32 * ks + 8 * g + j)) * 16 + le];
      f16 h, l;
      split2h(f, h, l);
      vh[j] = h;
      vl[j] = l;
    }
    *(f16x8*)(gwT + (size_t)i * 8) = vh;
    *(f16x8*)(gwT + 32768 + (size_t)i * 8) = vl;
  }
}

// ---------------------------------------------------------------------------
// Expert kernel. grid = 32 chunks(1024 rows) x 16 experts = 512 blocks;
// 256 thr (4 waves), 2 blocks/CU. Wave = it2 (32 oc cols). 16 tiles x 64 rows.
// Schedule/tile: stage_load(t+1) | flush eo(t-1) | GEMM1 | bar |
//                GEMM2 -> sEO | stage_write(t+1) | bar.
// LDS swizzle (sX/sH/sEO): elem [row][c] at row*128 + 8*((c>>3)^(row&7)) + (c&7).
__global__ __launch_bounds__(256, 2) void kexp(
    const float* __restrict__ x0, const f16* __restrict__ x1in,
    const f16* __restrict__ w1T, const f16* __restrict__ w2T,
    const float* __restrict__ b1, const float* __restrict__ b2,
    f16* __restrict__ eo, int layer) {
  __shared__ f16 sX[2][8192];  // 64 x 128, dbuf (32KB)
  __shared__ f16 sH[8192];     // 16KB
  __shared__ f16 sEO[8192];    // 16KB
  const int tid = threadIdx.x;
  const int lane = tid & 63;
  const int it2 = tid >> 6;
  const int g = lane >> 4, le = lane & 15;
  const int e = blockIdx.x & 15;
  const int r0 = (blockIdx.x >> 4) * 1024;
  const int te = e >> 1;
  const int lx = layer * 16 + e;

  // ---- resident single-fp16 weight fragments (it = 2*it2 + i2): 64 VGPR ----
  f16x8 w1r[2][4], w2r[2][4];
#pragma unroll
  for (int i2 = 0; i2 < 2; ++i2)
#pragma unroll
    for (int ks = 0; ks < 4; ++ks) {
      size_t fb = ((size_t)((lx * 4 + ks) * 8 + 2 * it2 + i2) * 64 + lane) * 8;
      w1r[i2][ks] = *(const f16x8*)(w1T + fb);
      w2r[i2][ks] = *(const f16x8*)(w2T + fb);
    }
  f32x4 b1v[2], b2v[2];
#pragma unroll
  for (int i2 = 0; i2 < 2; ++i2) {
    b1v[i2] = *(const f32x4*)(b1 + lx * 128 + 32 * it2 + 16 * i2 + 4 * g);
    b2v[i2] = *(const f32x4*)(b2 + lx * 128 + 32 * it2 + 16 * i2 + 4 * g);
  }

  // ---- async staging: thread -> row = tid>>2, granules gr..gr+3 ----
  const int srow = tid >> 2;
  const int gr = (tid & 3) * 4;
  f16x8 pre[4];
  auto stage_load = [&](int tile) {
    size_t base = ((size_t)(r0 + tile * 64 + srow) * 8 + te) * 128 + gr * 8;
    if (layer == 0) {
#pragma unroll
      for (int q = 0; q < 4; ++q) {
        f32x4 f0 = *(const f32x4*)(x0 + base + q * 8);
        f32x4 f1 = *(const f32x4*)(x0 + base + q * 8 + 4);
#pragma unroll
        for (int z = 0; z < 4; ++z) {
          pre[q][z] = (f16)f0[z];
          pre[q][4 + z] = (f16)f1[z];
        }
      }
    } else {
#pragma unroll
      for (int q = 0; q < 4; ++q)
        pre[q] = *(const f16x8*)(x1in + base + q * 8);
    }
  };
  auto stage_write = [&](int buf) {
#pragma unroll
    for (int q = 0; q < 4; ++q)
      *(f16x8*)(&sX[buf][srow * 128 + 8 * ((gr + q) ^ (srow & 7))]) = pre[q];
  };
  // ---- coalesced eo flush: 16 lanes x 16B contiguous per row ----
  auto eo_flush = [&](int tile) {
#pragma unroll
    for (int i = 0; i < 4; ++i) {
      int slot = i * 256 + tid;
      int row = slot >> 4, c = slot & 15;
      f16x8 v = *(const f16x8*)(&sEO[row * 128 + 8 * (c ^ (row & 7))]);
      *(f16x8*)(eo + ((size_t)(r0 + tile * 64 + row) * 16 + e) * 128 + 8 * c) = v;
    }
  };

  stage_load(0);
  stage_write(0);
  __syncthreads();

  for (int tile = 0; tile < 16; ++tile) {
    const int b = tile & 1;
    if (tile < 15) stage_load(tile + 1);
    if (tile > 0) eo_flush(tile - 1);
    // ---- GEMM1: h = relu(w1^T x^T + b1) -> sH ----
    {
      f32x4 a[2][4];
#pragma unroll
      for (int i2 = 0; i2 < 2; ++i2)
#pragma unroll
        for (int j = 0; j < 4; ++j) a[i2][j] = f32x4{0.f, 0.f, 0.f, 0.f};
#pragma unroll
      for (int ks = 0; ks < 4; ++ks)
#pragma unroll
        for (int j = 0; j < 4; ++j) {
          int brow = 16 * j + le;
          f16x8 bf = *(const f16x8*)(&sX[b][brow * 128 + 8 * ((4 * ks + g) ^ (brow & 7))]);
#pragma unroll
          for (int i2 = 0; i2 < 2; ++i2)
            a[i2][j] = MFMA(w1r[i2][ks], bf, a[i2][j]);
        }
#pragma unroll
      for (int i2 = 0; i2 < 2; ++i2)
#pragma unroll
        for (int j = 0; j < 4; ++j) {
          int brow = 16 * j + le;
          f16x4 hv;
#pragma unroll
          for (int r = 0; r < 4; ++r)
            hv[r] = (f16)fmaxf(a[i2][j][r] + b1v[i2][r], 0.f);
          *(f16x4*)(&sH[brow * 128 + 8 * ((4 * it2 + 2 * i2 + (g >> 1)) ^ (brow & 7)) +
                        4 * (g & 1)]) = hv;
        }
    }
    __syncthreads();  // sH ready; sEO flush-reads done before overwrite
    // ---- GEMM2: eo = relu(w2^T h^T + b2) -> sEO (frag-swizzled) ----
    {
      f32x4 a[2][4];
#pragma unroll
      for (int i2 = 0; i2 < 2; ++i2)
#pragma unroll
        for (int j = 0; j < 4; ++j) a[i2][j] = f32x4{0.f, 0.f, 0.f, 0.f};
#pragma unroll
      for (int ks = 0; ks < 4; ++ks)
#pragma unroll
        for (int j = 0; j < 4; ++j) {
          int brow = 16 * j + le;
          f16x8 bf = *(const f16x8*)(&sH[brow * 128 + 8 * ((4 * ks + g) ^ (brow & 7))]);
#pragma unroll
          for (int i2 = 0; i2 < 2; ++i2)
            a[i2][j] = MFMA(w2r[i2][ks], bf, a[i2][j]);
        }
#pragma unroll
      for (int i2 = 0; i2 < 2; ++i2)
#pragma unroll
        for (int j = 0; j < 4; ++j) {
          int brow = 16 * j + le;
          f16x4 ev;
#pragma unroll
          for (int r = 0; r < 4; ++r)
            ev[r] = (f16)fmaxf(a[i2][j][r] + b2v[i2][r], 0.f);
          *(f16x4*)(&sEO[brow * 128 + 8 * ((4 * it2 + 2 * i2 + (g >> 1)) ^ (brow & 7)) +
                         4 * (g & 1)]) = ev;
        }
    }
    if (tile < 15) stage_write(b ^ 1);
    // ---- pin weight residency across the loop (r14: init-pin failed) ----
#pragma unroll
    for (int i2 = 0; i2 < 2; ++i2)
#pragma unroll
      for (int ks = 0; ks < 4; ++ks) {
        asm volatile("" : "+v"(w1r[i2][ks]));
        asm volatile("" : "+v"(w2r[i2][ks]));
      }
    __syncthreads();
  }
  eo_flush(15);
}

// ---------------------------------------------------------------------------
// Gate + mix kernel (unchanged from r14). grid = 1024 blocks (32 rows), 512 thr.
__global__ __launch_bounds__(512, 4) void kmix(
    const float* __restrict__ x0, const f16* __restrict__ x1in,
    const f16* __restrict__ gwT, const float* __restrict__ gb,
    const float* __restrict__ sw, const f16* __restrict__ eo,
    f16* __restrict__ x1out, float* __restrict__ fout, int layer) {
  __shared__ float sG[8 * 16 * 32];  // [t][e][row32] 16KB
  const int tid = threadIdx.x;
  const int lane = tid & 63;
  const int t = tid >> 6;
  const int g = lane >> 4, le = lane & 15;
  const int r0 = blockIdx.x * 32;
  const int lt = layer * 8 + t;

  {  // ---- gates ----
    f32x4 l1[2], l2[2];
#pragma unroll
    for (int j = 0; j < 2; ++j) {
      l1[j] = f32x4{0.f, 0.f, 0.f, 0.f};
      l2[j] = f32x4{0.f, 0.f, 0.f, 0.f};
    }
#pragma unroll
    for (int ks = 0; ks < 4; ++ks) {
      size_t fb = ((size_t)(lt * 4 + ks) * 64 + lane) * 8;
      f16x8 ah = *(const f16x8*)(gwT + fb);
      f16x8 al = *(const f16x8*)(gwT + 32768 + fb);
#pragma unroll
      for (int j = 0; j < 2; ++j) {
        size_t xoff = ((size_t)(r0 + 16 * j + le) * 8 + t) * 128 + 32 * ks + 8 * g;
        f16x8 bf;
        if (layer == 0) {
          f32x4 f0 = *(const f32x4*)(x0 + xoff);
          f32x4 f1 = *(const f32x4*)(x0 + xoff + 4);
#pragma unroll
          for (int z = 0; z < 4; ++z) {
            bf[z] = (f16)f0[z];
            bf[4 + z] = (f16)f1[z];
          }
        } else {
          bf = *(const f16x8*)(x1in + xoff);
        }
        l1[j] = MFMA(ah, bf, l1[j]);
        l2[j] = MFMA(al, bf, l2[j]);
      }
    }
#pragma unroll
    for (int j = 0; j < 2; ++j) {
      float zb[4];
#pragma unroll
      for (int r = 0; r < 4; ++r)
        zb[r] = l1[j][r] + l2[j][r] * LOSC + gb[lt * 16 + 4 * g + r];
      float m4 = fmaxf(fmaxf(zb[0], zb[1]), fmaxf(zb[2], zb[3]));
      m4 = fmaxf(m4, __shfl_xor(m4, 16, 64));
      m4 = fmaxf(m4, __shfl_xor(m4, 32, 64));
      float p4[4], s4 = 0.f;
#pragma unroll
      for (int r = 0; r < 4; ++r) {
        p4[r] = __expf(zb[r] - m4);
        s4 += p4[r];
      }
      s4 += __shfl_xor(s4, 16, 64);
      s4 += __shfl_xor(s4, 32, 64);
      float inv = 1.f / s4;
#pragma unroll
      for (int r = 0; r < 4; ++r)
        sG[(t * 16 + 4 * g + r) * 32 + 16 * j + le] = p4[r] * inv;
    }
  }
  __syncthreads();

  // ---- mix ----
  const int lrow = tid >> 4;
  const int grow = r0 + lrow;
  const int c0 = (tid & 15) * 8;
  f32x4 am[8][2];
#pragma unroll
  for (int tt = 0; tt < 8; ++tt)
#pragma unroll
    for (int k = 0; k < 2; ++k) am[tt][k] = f32x4{0.f, 0.f, 0.f, 0.f};

  for (int ee = 0; ee < 16; ++ee) {
    const int tte = ee >> 1, eh = ee & 1;
    f16x8 ev = *(const f16x8*)(eo + ((size_t)grow * 16 + ee) * 128 + c0);
    float evf[8];
#pragma unroll
    for (int z = 0; z < 8; ++z) evf[z] = (float)ev[z];
    float ssew = sw[(layer * 8 + tte) * 2 + eh];
#pragma unroll
    for (int tt = 0; tt < 8; ++tt) {
      float coef = sG[(tt * 16 + ee) * 32 + lrow] + (tt == tte ? ssew : 0.f);
#pragma unroll
      for (int z = 0; z < 8; ++z)
        am[tt][z >> 2][z & 3] = fmaf(coef, evf[z], am[tt][z >> 2][z & 3]);
    }
  }
#pragma unroll
  for (int tt = 0; tt < 8; ++tt) {
    size_t off = ((size_t)grow * 8 + tt) * 128 + c0;
    if (layer == 0) {
      f16x8 hv;
#pragma unroll
      for (int z = 0; z < 8; ++z) hv[z] = (f16)am[tt][z >> 2][z & 3];
      *(f16x8*)(x1out + off) = hv;
    } else {
      *(f32x4*)(fout + off) = am[tt][0];
      *(f32x4*)(fout + off + 4) = am[tt][1];
    }
  }
}

// ---------------------------------------------------------------------------
extern "C" void kernel_launch(void* const* d_in, const int* in_sizes, int n_in,
                              void* d_out, int out_size, void* d_ws, size_t ws_size,
                              hipStream_t stream) {
  const float* x0 = (const float*)d_in[0];
  const float* w1 = (const float*)d_in[1];
  const float* b1 = (const float*)d_in[2];
  const float* w2 = (const float*)d_in[3];
  const float* b2 = (const float*)d_in[4];
  const float* gw = (const float*)d_in[5];
  const float* gb = (const float*)d_in[6];
  const float* sw = (const float*)d_in[7];

  // ws bytes: w1T [0,1MB) | w2T [1MB,2MB) | gwT pair [2MB,+128KB)
  // | x1h fp16 [4MB,+64MB) | eo fp16 [68MB,+128MB)
  f16* w1T = (f16*)d_ws;
  f16* w2T = (f16*)((char*)d_ws + 1048576);
  f16* gwT = (f16*)((char*)d_ws + 2097152);
  f16* x1h = (f16*)((char*)d_ws + 4194304);
  f16* eo = (f16*)((char*)d_ws + 71303168);
  float* out = (float*)d_out;

  kxform<<<528, 256, 0, stream>>>(w1, w2, gw, w1T, w2T, gwT);

  kexp<<<512, 256, 0, stream>>>(x0, nullptr, w1T, w2T, b1, b2, eo, 0);
  kmix<<<1024, 512, 0, stream>>>(x0, nullptr, gwT, gb, sw, eo, x1h, nullptr, 0);
  kexp<<<512, 256, 0, stream>>>(nullptr, x1h, w1T, w2T, b1, b2, eo, 1);
  kmix<<<1024, 512, 0, stream>>>(nullptr, x1h, gwT, gb, sw, eo, nullptr, out, 1);
}